// Round 16
// baseline (1236.180 us; speedup 1.0000x reference)
//
#include <hip/hip_runtime.h>
#include <stdint.h>

// Net_11587821765063: sequential SNN scan, T=1000 steps.
// Output = spike_out (T,1,COUT) float32 only; w / traces are not returned.
//
// Math reductions (absmax 0 in rounds 1-15):
//  - potentiation p[t][i] = 2 if x[t][i] else (1 if (t==0 or x[t-1][i]) else 0)
//  - depression for row o at t = -x[t][i] iff (!spike[t][o] && spike[t-1][o]),
//    spike[-1] := true (cout init quirk).
//  - prohibit P[t] = 1 iff any spike at t-1 (grid-wide 1-bit OR); P[0]=0.
//
// Round 16 = r15 (autonomous 1-row waves, 2-step speculation, selfdec) +
//  1. 2 waves/SIMD: 64 blocks x 8 waves (512 one-row waves) — co-resident
//     wave fills the ~80% latency bubbles r15 exposed at 1 wave/SIMD.
//  2. LDS soft-sync selfdec over the block's 8 rows (NO barrier): each wave
//     posts (u+1)<<4|hb into an 8-deep LDS ring; at step u all waves read
//     the 8 words for u-2 (issued at loop top, checked after the dot), OR
//     them -> block hh(u-2); selfdec rate 1-0.12^8 ~ 1. Global gather runs
//     only on the ~never fallback. Skew bound: every wave needs siblings
//     >= u-2 -> max skew 2 < ring depth 8 (no overwrite, no deadlock).
//  3. code prefetch 3 iterations deep (cw/cwn/cwnn).
// FP per wave verbatim from r15 (dot order, 6-stage eq butterfly, 7-op
// fold2, branchy updates, out-bit batching) -> absmax 0.

#define T_STEPS 1000
#define CIN     784
#define COUT    512
#define CPL     13            // columns per lane (64*13 = 832 >= 784)
#define NROW    512           // one publish byte per row per step
#define NBLK    64
#define WPB     8             // waves per block, 1 row per wave
#define VTHR_F   12500.0f
#define PROHIB_F 11250.0f

#define SLOTS_BYTES (T_STEPS * NROW)          // 512000 B
#define CODE_OFFSET 524288                    // 512 KiB >= 512000 B of slots

// ---- prep: zero slot bytes and pack per-(t,lane) 16-byte code slot:
// byte j (j<13) encodes col = lane*13+j: bit0 = x[t][col], bits[2:1] = p.
__global__ __launch_bounds__(256) void prep_kernel(const int* __restrict__ x,
                                                   uint8_t* __restrict__ code,
                                                   uint2* __restrict__ slots2) {
    int gid = blockIdx.x * blockDim.x + threadIdx.x;   // one per (t, lane)
    if (gid >= T_STEPS * 64) return;
    slots2[gid] = make_uint2(0u, 0u);                  // 64000 x 8B = 512000 B
    int t = gid >> 6;
    int lane = gid & 63;
    uint32_t wds[4] = {0u, 0u, 0u, 0u};
    #pragma unroll
    for (int j = 0; j < CPL; ++j) {
        int col = lane * CPL + j;
        uint32_t b = 0u;
        if (col < CIN) {
            int xc = x[t * CIN + col];
            int xp = (t > 0) ? x[(t - 1) * CIN + col] : 0;
            int p = xc ? 2 : ((t == 0) ? 1 : (xp ? 1 : 0));
            b = (uint32_t)((xc & 1) | (p << 1));
        }
        wds[j >> 2] |= b << ((j & 3) * 8);
    }
    ((uint4*)code)[gid] = make_uint4(wds[0], wds[1], wds[2], wds[3]);
}

__device__ __forceinline__ int rfl(bool b) {      // force SGPR / s_cbranch
    return __builtin_amdgcn_readfirstlane(b ? 1 : 0);
}

// scan one gathered uint64 (8 row-bytes): present = high nibble 0xB;
// set = present && hypothesis bit kk.
__device__ __forceinline__ void scan8(unsigned long long gv, int kk,
                                      bool& anyset, bool& allp) {
    anyset = false; allp = true;
    #pragma unroll
    for (int i = 0; i < 8; ++i) {
        uint32_t b = (uint32_t)(gv >> (8 * i)) & 0xFFu;
        bool p = (b & 0xF0u) == 0xB0u;
        allp = allp && p;
        anyset = anyset || (p && (((b >> kk) & 1u) != 0u));
    }
}

__global__ __launch_bounds__(512, 1) void snn_kernel(const float* __restrict__ weight,
                                                     const uint8_t* __restrict__ code,
                                                     uint8_t* __restrict__ slots,
                                                     float* __restrict__ out) {
    __shared__ int sh[8][WPB];             // 8-deep ring: (tag<<4)|hb per wave

    const int tid  = threadIdx.x;
    const int wave = tid >> 6;
    const int lane = tid & 63;
    const int row  = blockIdx.x * WPB + wave;  // 512 one-row waves

    if (lane == 0) {
        #pragma unroll
        for (int s = 0; s < 8; ++s) sh[s][wave] = 0;
    }
    __syncthreads();                       // one-time init barrier only

    float wA[CPL], wB[CPL];
    #pragma unroll
    for (int j = 0; j < CPL; ++j) {
        int col = lane * CPL + j;
        float v = (col < CIN) ? weight[row * CIN + col] : 0.0f;
        wA[j] = v; wB[j] = v;
    }

    const uint4* code4 = (const uint4*)code;
    uint4 cw   = code4[lane];              // codes for u=0
    uint4 cwn  = code4[64 + lane];         // codes for u=1
    uint4 cwnn = code4[128 + lane];        // codes for u=2

    float memA = 0.0f, memB = 0.0f;
    bool  psA = true, psB = true;          // spike(-1)=true quirk
    bool  eq  = true;                      // wB == wA (and memB==memA, psB==psA)
    int p2 = 0, p3 = 0;                    // actual P[u-2], P[u-3]
    uint32_t myb = 0u;                     // out bits: step v when v%64==lane

    for (int u = 0; u < T_STEPS; ++u) {
        // ---- top-of-loop issues: code load for u+3, LDS loads for hh(u-2) ----
        uint4 cw3 = (u + 3 < T_STEPS) ? code4[(size_t)(u + 3) * 64 + lane]
                                      : make_uint4(0u, 0u, 0u, 0u);
        int tv[WPB];
        const int rs = (u >= 2) ? ((u - 2) & 7) : 0;
        #pragma unroll
        for (int w = 0; w < WPB; ++w)
            tv[w] = __hip_atomic_load(&sh[rs][w], __ATOMIC_RELAXED,
                                      __HIP_MEMORY_SCOPE_WORKGROUP);

        // ---- decode x bits for step u; dot(s) ----
        uint32_t cwd[4] = {cw.x, cw.y, cw.z, cw.w};
        float xf[CPL];
        #pragma unroll
        for (int j = 0; j < CPL; ++j)
            xf[j] = (float)((cwd[j >> 2] >> ((j & 3) * 8)) & 1u);
        float dA = 0.0f;
        #pragma unroll
        for (int j = 0; j < CPL; ++j) dA += xf[j] * wA[j];   // exact: x in {0,1}

        float dotA, dotB;
        if (rfl(eq)) {
            // 6-stage butterfly (r13/r15 eq-case, validated)
            float k0 = dA;
            k0 += __shfl_xor(k0, 32, 64);
            k0 += __shfl_xor(k0, 16, 64);
            k0 += __shfl_xor(k0, 8, 64);
            k0 += __shfl_xor(k0, 4, 64);
            k0 += __shfl_xor(k0, 2, 64);
            k0 += __shfl_xor(k0, 1, 64);
            dotA = k0; dotB = k0;
        } else {
            float dB = 0.0f;
            #pragma unroll
            for (int j = 0; j < CPL; ++j) dB += xf[j] * wB[j];
            // 7-op fold2 (r7, validated)
            bool hi = (lane & 32) != 0;
            float k0 = hi ? dB : dA;
            float s0 = hi ? dA : dB;
            k0 += __shfl_xor(s0, 32, 64);
            k0 += __shfl_xor(k0, 16, 64);
            k0 += __shfl_xor(k0, 8, 64);
            k0 += __shfl_xor(k0, 4, 64);
            k0 += __shfl_xor(k0, 2, 64);
            k0 += __shfl_xor(k0, 1, 64);
            float ot = __shfl_xor(k0, 32, 64);
            dotA = hi ? ot : k0;
            dotB = hi ? k0 : ot;
        }

        // ---- 4 hypotheses (d = P[u-1] branch, c = P[u] branch) ----
        float sa = memA + dotA;            // reference op order
        float sb = memB + dotB;
        float m00 = fmaxf(sa, 0.0f),            m01 = fmaxf(sa - PROHIB_F, 0.0f);
        float m10 = fmaxf(sb, 0.0f),            m11 = fmaxf(sb - PROHIB_F, 0.0f);
        bool s00 = m00 >= VTHR_F, s01 = m01 >= VTHR_F;
        bool s10 = m10 >= VTHR_F, s11 = m11 >= VTHR_F;
        int hb = (s00 ? 1 : 0) | (s01 ? 2 : 0) | (s10 ? 4 : 0) | (s11 ? 8 : 0);

        // ---- post hb(u): LDS ring (soft-sync) + global byte (fallback) ----
        if (lane == 0) {
            __hip_atomic_store(&sh[u & 7][wave], ((u + 1) << 4) | hb,
                               __ATOMIC_RELAXED, __HIP_MEMORY_SCOPE_WORKGROUP);
            __hip_atomic_store(&slots[(size_t)u * NROW + row],
                               (uint8_t)(0xB0u | (uint32_t)hb),
                               __ATOMIC_RELAXED, __HIP_MEMORY_SCOPE_AGENT);
        }

        // ---- resolve P[u-1]: block hh(u-2) selfdec (~always) / fallback ----
        const int kk = (p3 << 1) | p2;                 // (P[u-3]<<1)|P[u-2]
        int bst = 0;
        if (u >= 2) {
            const int want = u - 1;                    // tag for step u-2
            for (;;) {
                bool ok = true;
                #pragma unroll
                for (int w = 0; w < WPB; ++w) ok = ok && ((tv[w] >> 4) >= want);
                if (ok) break;
                #pragma unroll
                for (int w = 0; w < WPB; ++w)
                    tv[w] = __hip_atomic_load(&sh[rs][w], __ATOMIC_RELAXED,
                                              __HIP_MEMORY_SCOPE_WORKGROUP);
            }
            int hh = 0;
            #pragma unroll
            for (int w = 0; w < WPB; ++w) hh |= tv[w] & 15;
            if (rfl(((hh >> kk) & 1) != 0)) {
                bst = 1;                   // some row in block spiked at u-2
            } else {
                // ~never: gather the global per-row table for step u-2
                const unsigned long long* gl =
                    (const unsigned long long*)(slots + (size_t)(u - 2) * NROW);
                unsigned long long gv;
                for (;;) {
                    gv = __hip_atomic_load(&gl[lane], __ATOMIC_RELAXED,
                                           __HIP_MEMORY_SCOPE_AGENT);
                    bool anyset, allp;
                    scan8(gv, kk, anyset, allp);
                    if (__any((int)anyset)) { bst = 1; break; }
                    if (__all((int)allp)) { bst = 0; break; }
                    __builtin_amdgcn_s_sleep(1);
                }
            }
        }
        p3 = p2; p2 = bst;

        // ---- collapse branch d=bst; record out bit; rebranch over c=P[u] ----
        bool sprv = bst ? psB : psA;                   // actual spike(u-1)
        bool sc0  = bst ? s10 : s00;                   // spike under c=0
        bool sc1  = bst ? s11 : s01;                   // spike under c=1
        float mc0 = bst ? m10 : m00;
        float mc1 = bst ? m11 : m01;

        if (u >= 1) {
            int v = u - 1;
            if ((v & 63) == lane) myb |= (sprv ? 1u : 0u) << (v >> 6);
        }

        memA = sc0 ? 0.0f : mc0;
        memB = sc1 ? 0.0f : mc1;
        bool eqNext = (sc0 == sc1) && (memA == memB);

        // collapse weights to the resolved d-branch (only if they differ)
        if (rfl(bst && !eq)) {
            #pragma unroll
            for (int j = 0; j < CPL; ++j) wA[j] = wB[j];
        }
        // wave-uniform branchy updates: only the taken path issues
        if (rfl(eqNext)) {
            if (rfl(sc0)) {                // potentiate (common path)
                #pragma unroll
                for (int j = 0; j < CPL; ++j) {
                    float pfj = (float)((cwd[j >> 2] >> ((j & 3) * 8 + 1)) & 3u);
                    wA[j] = fminf(wA[j] + pfj, 127.0f);
                }
            } else if (rfl(sprv)) {        // depress
                #pragma unroll
                for (int j = 0; j < CPL; ++j)
                    wA[j] = fmaxf(wA[j] - xf[j], 0.0f);
            }
            // wB stale; eq flag covers it
        } else {
            // divergent: build wB from pre-update wA base (c=1 path)
            if (rfl(sc1)) {
                #pragma unroll
                for (int j = 0; j < CPL; ++j) {
                    float pfj = (float)((cwd[j >> 2] >> ((j & 3) * 8 + 1)) & 3u);
                    wB[j] = fminf(wA[j] + pfj, 127.0f);
                }
            } else if (rfl(sprv)) {
                #pragma unroll
                for (int j = 0; j < CPL; ++j)
                    wB[j] = fmaxf(wA[j] - xf[j], 0.0f);
            } else {
                #pragma unroll
                for (int j = 0; j < CPL; ++j) wB[j] = wA[j];
            }
            if (rfl(sc0)) {                // c=0 path in place
                #pragma unroll
                for (int j = 0; j < CPL; ++j) {
                    float pfj = (float)((cwd[j >> 2] >> ((j & 3) * 8 + 1)) & 3u);
                    wA[j] = fminf(wA[j] + pfj, 127.0f);
                }
            } else if (rfl(sprv)) {
                #pragma unroll
                for (int j = 0; j < CPL; ++j)
                    wA[j] = fmaxf(wA[j] - xf[j], 0.0f);
            }
        }
        psA = sc0; psB = sc1; eq = eqNext;

        cw = cwn; cwn = cwnn; cwnn = cw3;
    }

    // ---- epilogue: resolve P[T-1] via hh(T-2), write this row's outputs ----
    {
        const int kk = (p3 << 1) | p2;
        const int rs = (T_STEPS - 2) & 7;
        const int want = T_STEPS - 1;
        int tv[WPB];
        for (;;) {
            bool ok = true;
            #pragma unroll
            for (int w = 0; w < WPB; ++w) {
                tv[w] = __hip_atomic_load(&sh[rs][w], __ATOMIC_RELAXED,
                                          __HIP_MEMORY_SCOPE_WORKGROUP);
                ok = ok && ((tv[w] >> 4) >= want);
            }
            if (ok) break;
        }
        int hh = 0;
        #pragma unroll
        for (int w = 0; w < WPB; ++w) hh |= tv[w] & 15;
        int cst;
        if (rfl(((hh >> kk) & 1) != 0)) {
            cst = 1;
        } else {
            const unsigned long long* gl2 =
                (const unsigned long long*)(slots + (size_t)(T_STEPS - 2) * NROW);
            unsigned long long gv2;
            for (;;) {
                gv2 = __hip_atomic_load(&gl2[lane], __ATOMIC_RELAXED,
                                        __HIP_MEMORY_SCOPE_AGENT);
                bool anyset, allp;
                scan8(gv2, kk, anyset, allp);
                if (__any((int)anyset)) { cst = 1; break; }
                if (__all((int)allp)) { cst = 0; break; }
                __builtin_amdgcn_s_sleep(1);
            }
        }
        bool sr = cst ? psB : psA;
        {
            int v = T_STEPS - 1;
            if ((v & 63) == lane) myb |= (sr ? 1u : 0u) << (v >> 6);
        }
        #pragma unroll
        for (int b = 0; b < 16; ++b) {
            int s = b * 64 + lane;
            if (s < T_STEPS)
                out[(size_t)s * COUT + row] = (float)((myb >> b) & 1u);
        }
    }
}

extern "C" void kernel_launch(void* const* d_in, const int* in_sizes, int n_in,
                              void* d_out, int out_size, void* d_ws, size_t ws_size,
                              hipStream_t stream) {
    const int*   x      = (const int*)d_in[0];     // (T,1,CIN) int32
    const float* weight = (const float*)d_in[1];   // (COUT,CIN) f32
    float* out = (float*)d_out;                    // (T,1,COUT) f32

    uint8_t* slots = (uint8_t*)d_ws;
    uint8_t* code  = (uint8_t*)d_ws + CODE_OFFSET;

    int prep_threads = T_STEPS * 64;
    prep_kernel<<<(prep_threads + 255) / 256, 256, 0, stream>>>(x, code,
                                                                (uint2*)slots);
    snn_kernel<<<NBLK, WPB * 64, 0, stream>>>(weight, code, slots, out);
}

// Round 17
// 1179.734 us; speedup vs baseline: 1.0478x; 1.0478x over previous
//
#include <hip/hip_runtime.h>
#include <stdint.h>

// Net_11587821765063: sequential SNN scan, T=1000 steps.
// Output = spike_out (T,1,COUT) float32 only; w / traces are not returned.
//
// Math reductions (absmax 0 in rounds 1-16):
//  - potentiation p[t][i] = 2 if x[t][i] else (1 if (t==0 or x[t-1][i]) else 0)
//  - depression for row o at t = -x[t][i] iff (!spike[t][o] && spike[t-1][o]),
//    spike[-1] := true (cout init quirk).
//  - prohibit P[t] = 1 iff any spike at t-1 (grid-wide 1-bit OR); P[0]=0.
//
// Round 17 = r15 (champion: 512 autonomous 1-row waves on 512 SIMDs,
// 2-step speculation, own-row selfdec, byte publish, out-bit batching)
// with the branch scaffolding removed — STRAIGHT-LINE common path:
//  - merged if-converted update w' = max(min(w + s*pf,127) - d*xf, 0),
//    bit-identical to the branchy sequence (s,d mutually exclusive 0/1
//    floats; w in [0,127] invariant makes inactive clamps no-ops; fma with
//    0/1 multiplier = plain add/sub single-rounded).
//  - base-select bst?wB:wA via cndmask (when branches agree wB==wA bitwise).
//  - eq machinery dropped: dB + 7-op fold2 ALWAYS (r7's validated path).
//  - xf/pf decode for u+1 pipelined into iteration u (off the w->dot chain).
// Remaining branches: rare fallback gather spin + loop. All FP sequences
// verbatim from validated rounds -> absmax 0.

#define T_STEPS 1000
#define CIN     784
#define COUT    512
#define CPL     13            // columns per lane (64*13 = 832 >= 784)
#define NROW    512           // one publish byte per row per step
#define VTHR_F   12500.0f
#define PROHIB_F 11250.0f

#define SLOTS_BYTES (T_STEPS * NROW)          // 512000 B
#define CODE_OFFSET 524288                    // 512 KiB >= 512000 B of slots

// ---- prep: zero slot bytes and pack per-(t,lane) 16-byte code slot:
// byte j (j<13) encodes col = lane*13+j: bit0 = x[t][col], bits[2:1] = p.
__global__ __launch_bounds__(256) void prep_kernel(const int* __restrict__ x,
                                                   uint8_t* __restrict__ code,
                                                   uint2* __restrict__ slots2) {
    int gid = blockIdx.x * blockDim.x + threadIdx.x;   // one per (t, lane)
    if (gid >= T_STEPS * 64) return;
    slots2[gid] = make_uint2(0u, 0u);                  // 64000 x 8B = 512000 B
    int t = gid >> 6;
    int lane = gid & 63;
    uint32_t wds[4] = {0u, 0u, 0u, 0u};
    #pragma unroll
    for (int j = 0; j < CPL; ++j) {
        int col = lane * CPL + j;
        uint32_t b = 0u;
        if (col < CIN) {
            int xc = x[t * CIN + col];
            int xp = (t > 0) ? x[(t - 1) * CIN + col] : 0;
            int p = xc ? 2 : ((t == 0) ? 1 : (xp ? 1 : 0));
            b = (uint32_t)((xc & 1) | (p << 1));
        }
        wds[j >> 2] |= b << ((j & 3) * 8);
    }
    ((uint4*)code)[gid] = make_uint4(wds[0], wds[1], wds[2], wds[3]);
}

// scan one gathered uint64 (8 row-bytes): present = high nibble 0xB;
// set = present && hypothesis bit kk.
__device__ __forceinline__ void scan8(unsigned long long gv, int kk,
                                      bool& anyset, bool& allp) {
    anyset = false; allp = true;
    #pragma unroll
    for (int i = 0; i < 8; ++i) {
        uint32_t b = (uint32_t)(gv >> (8 * i)) & 0xFFu;
        bool p = (b & 0xF0u) == 0xB0u;
        allp = allp && p;
        anyset = anyset || (p && (((b >> kk) & 1u) != 0u));
    }
}

__device__ __forceinline__ void decode_code(const uint4& c, float* xf, float* pf) {
    uint32_t cwd[4] = {c.x, c.y, c.z, c.w};
    #pragma unroll
    for (int j = 0; j < CPL; ++j) {
        uint32_t byte = (cwd[j >> 2] >> ((j & 3) * 8)) & 0xFFu;
        xf[j] = (float)(byte & 1u);
        pf[j] = (float)(byte >> 1);
    }
}

__global__ __launch_bounds__(256, 1) void snn_kernel(const float* __restrict__ weight,
                                                     const uint8_t* __restrict__ code,
                                                     uint8_t* __restrict__ slots,
                                                     float* __restrict__ out) {
    const int tid  = threadIdx.x;
    const int wave = tid >> 6;
    const int lane = tid & 63;
    const int row  = blockIdx.x * 4 + wave;    // 512 autonomous waves

    float wA[CPL], wB[CPL];
    #pragma unroll
    for (int j = 0; j < CPL; ++j) {
        int col = lane * CPL + j;
        float v = (col < CIN) ? weight[row * CIN + col] : 0.0f;
        wA[j] = v; wB[j] = v;
    }

    const uint4* code4 = (const uint4*)code;
    // pipeline: xfc/pfc = decoded codes for current step u; cwn = codes u+1
    float xfc[CPL], pfc[CPL];
    {
        uint4 c0 = code4[lane];
        decode_code(c0, xfc, pfc);
    }
    uint4 cwn = code4[64 + lane];

    float memA = 0.0f, memB = 0.0f;
    bool  psA = true, psB = true;          // spike(-1)=true quirk
    int p2 = 0, p3 = 0;                    // actual P[u-2], P[u-3]
    int hb_m1 = 0, hb_m2 = 0;              // own row hb(u-1), hb(u-2)
    uint32_t myb = 0u;                     // out bits: step v when v%64==lane

    for (int u = 0; u < T_STEPS; ++u) {
        // ---- top-of-loop issues: code load for u+2, gated gather for u-2 ----
        uint4 cw2 = (u + 2 < T_STEPS) ? code4[(size_t)(u + 2) * 64 + lane]
                                      : make_uint4(0u, 0u, 0u, 0u);
        const int kk = (p3 << 1) | p2;                 // (P[u-3]<<1)|P[u-2]
        const bool selfdec = (u >= 2) && (((hb_m2 >> kk) & 1) != 0);
        const unsigned long long* gl =
            (const unsigned long long*)(slots + (size_t)(u >= 2 ? u - 2 : 0) * NROW);
        unsigned long long gv = 0xB0B0B0B0B0B0B0B0ull; // sentinel-passing dummy
        if (u >= 2 && !selfdec)
            gv = __hip_atomic_load(&gl[lane], __ATOMIC_RELAXED,
                                   __HIP_MEMORY_SCOPE_AGENT);

        // ---- dots for both branches (validated order) ----
        float dA = 0.0f, dB = 0.0f;
        #pragma unroll
        for (int j = 0; j < CPL; ++j) {
            dA += xfc[j] * wA[j];          // exact: x in {0,1}
            dB += xfc[j] * wB[j];
        }

        // ---- 7-op fold2 (r7, validated always-on) ----
        bool hi = (lane & 32) != 0;
        float k0 = hi ? dB : dA;
        float s0 = hi ? dA : dB;
        k0 += __shfl_xor(s0, 32, 64);
        k0 += __shfl_xor(k0, 16, 64);
        k0 += __shfl_xor(k0, 8, 64);
        k0 += __shfl_xor(k0, 4, 64);
        k0 += __shfl_xor(k0, 2, 64);
        k0 += __shfl_xor(k0, 1, 64);
        float ot = __shfl_xor(k0, 32, 64);
        float dotA = hi ? ot : k0;
        float dotB = hi ? k0 : ot;

        // ---- pipelined decode of step u+1's codes (off the w->dot chain) ----
        float xfn[CPL], pfn[CPL];
        decode_code(cwn, xfn, pfn);

        // ---- 4 hypotheses (d = P[u-1] branch, c = P[u] branch) ----
        float sa = memA + dotA;            // reference op order
        float sb = memB + dotB;
        float m00 = fmaxf(sa, 0.0f),            m01 = fmaxf(sa - PROHIB_F, 0.0f);
        float m10 = fmaxf(sb, 0.0f),            m11 = fmaxf(sb - PROHIB_F, 0.0f);
        bool s00 = m00 >= VTHR_F, s01 = m01 >= VTHR_F;
        bool s10 = m10 >= VTHR_F, s11 = m11 >= VTHR_F;
        int hb = (s00 ? 1 : 0) | (s01 ? 2 : 0) | (s10 ? 4 : 0) | (s11 ? 8 : 0);

        // ---- publish own row's hb(u) immediately (fire-and-forget byte) ----
        if (lane == 0)
            __hip_atomic_store(&slots[(size_t)u * NROW + row],
                               (uint8_t)(0xB0u | (uint32_t)hb),
                               __ATOMIC_RELAXED, __HIP_MEMORY_SCOPE_AGENT);

        // ---- resolve P[u-1]: own-row selfdec (88%) or global fallback ----
        int bst = 0;
        if (u >= 2) {
            if (selfdec) {
                bst = 1;                   // own row spiked at u-2
            } else {
                for (;;) {
                    bool anyset, allp;
                    scan8(gv, kk, anyset, allp);
                    if (__any((int)anyset)) { bst = 1; break; }
                    if (__all((int)allp)) { bst = 0; break; }
                    __builtin_amdgcn_s_sleep(1);       // backoff (rare path)
                    gv = __hip_atomic_load(&gl[lane], __ATOMIC_RELAXED,
                                           __HIP_MEMORY_SCOPE_AGENT);
                }
            }
        }
        p3 = p2; p2 = bst;
        hb_m2 = hb_m1; hb_m1 = hb;

        // ---- collapse branch d=bst; record out bit; rebranch over c=P[u] ----
        bool sprv = bst ? psB : psA;                   // actual spike(u-1)
        bool sc0  = bst ? s10 : s00;                   // spike under c=0
        bool sc1  = bst ? s11 : s01;                   // spike under c=1
        float mc0 = bst ? m10 : m00;
        float mc1 = bst ? m11 : m01;

        if (u >= 1) {
            int v = u - 1;
            if ((v & 63) == lane) myb |= (sprv ? 1u : 0u) << (v >> 6);
        }

        memA = sc0 ? 0.0f : mc0;
        memB = sc1 ? 0.0f : mc1;

        // ---- merged if-converted updates (value-exact, no branches) ----
        float s0f = sc0 ? 1.0f : 0.0f;
        float s1f = sc1 ? 1.0f : 0.0f;
        float d0f = (!sc0 && sprv) ? 1.0f : 0.0f;      // mutually exclusive
        float d1f = (!sc1 && sprv) ? 1.0f : 0.0f;
        #pragma unroll
        for (int j = 0; j < CPL; ++j) {
            float base = bst ? wB[j] : wA[j];          // wB==wA when agreed
            float ta = fminf(fmaf(s0f, pfc[j], base), 127.0f);
            wA[j] = fmaxf(fmaf(-d0f, xfc[j], ta), 0.0f);
            float tb = fminf(fmaf(s1f, pfc[j], base), 127.0f);
            wB[j] = fmaxf(fmaf(-d1f, xfc[j], tb), 0.0f);
        }
        psA = sc0; psB = sc1;

        // ---- rotate pipelines ----
        #pragma unroll
        for (int j = 0; j < CPL; ++j) { xfc[j] = xfn[j]; pfc[j] = pfn[j]; }
        cwn = cw2;
    }

    // ---- epilogue: resolve P[T-1], record last bit, write this row's out ----
    {
        const int kk = (p3 << 1) | p2;
        int cst;
        if (((hb_m2 >> kk) & 1) != 0) {
            cst = 1;                       // own row forced the OR
        } else {
            const unsigned long long* gl2 =
                (const unsigned long long*)(slots + (size_t)(T_STEPS - 2) * NROW);
            unsigned long long gv2;
            for (;;) {
                gv2 = __hip_atomic_load(&gl2[lane], __ATOMIC_RELAXED,
                                        __HIP_MEMORY_SCOPE_AGENT);
                bool anyset, allp;
                scan8(gv2, kk, anyset, allp);
                if (__any((int)anyset)) { cst = 1; break; }
                if (__all((int)allp)) { cst = 0; break; }
                __builtin_amdgcn_s_sleep(1);
            }
        }
        bool sr = cst ? psB : psA;
        {
            int v = T_STEPS - 1;
            if ((v & 63) == lane) myb |= (sr ? 1u : 0u) << (v >> 6);
        }
        // write this row's 1000 spike floats from the bit register
        #pragma unroll
        for (int b = 0; b < 16; ++b) {
            int s = b * 64 + lane;
            if (s < T_STEPS)
                out[(size_t)s * COUT + row] = (float)((myb >> b) & 1u);
        }
    }
}

extern "C" void kernel_launch(void* const* d_in, const int* in_sizes, int n_in,
                              void* d_out, int out_size, void* d_ws, size_t ws_size,
                              hipStream_t stream) {
    const int*   x      = (const int*)d_in[0];     // (T,1,CIN) int32
    const float* weight = (const float*)d_in[1];   // (COUT,CIN) f32
    float* out = (float*)d_out;                    // (T,1,COUT) f32

    uint8_t* slots = (uint8_t*)d_ws;
    uint8_t* code  = (uint8_t*)d_ws + CODE_OFFSET;

    int prep_threads = T_STEPS * 64;
    prep_kernel<<<(prep_threads + 255) / 256, 256, 0, stream>>>(x, code,
                                                                (uint2*)slots);
    snn_kernel<<<128, 256, 0, stream>>>(weight, code, slots, out);
}

// Round 19
// 1047.615 us; speedup vs baseline: 1.1800x; 1.1261x over previous
//
#include <hip/hip_runtime.h>
#include <stdint.h>

// Net_11587821765063: sequential SNN scan, T=1000 steps.
// Output = spike_out (T,1,COUT) float32 only; w / traces are not returned.
//
// Math reductions (absmax 0 in rounds 1-17):
//  - potentiation p[t][i] = 2 if x[t][i] else (1 if (t==0 or x[t-1][i]) else 0)
//  - depression for row o at t = -x[t][i] iff (!spike[t][o] && spike[t-1][o]),
//    spike[-1] := true (cout init quirk).
//  - prohibit P[t] = 1 iff any spike at t-1 (grid-wide 1-bit OR); P[0]=0.
//
// Round 19 = round 18 with the compile error fixed (DPP ctrl must be a
// constant -> template parameter). Structure unchanged from r17 champion
// (512 autonomous 1-row waves, 2-step speculation, selfdec, straight-line
// updates); the LDS-pipe shuffle chain is replaced by a FAST CROSS-LANE
// REDUCTION with bit-identical pairing:
//   stage32: v_permlane32_swap_b32 sum-form (copy+swap -> halves exchanged;
//            sum = v[l]+v[l^32] every lane; add commutes bitwise-exactly)
//   stage16: v_permlane16_swap_b32 sum-form (rows 0<->1, 2<->3 = xor16)
//   stage8 : DPP row_ror:8 == xor8 within 16-lane rows
//   stage4 : ds_swizzle 0x101F (xor4) — lone LDS op
//   stage2 : DPP quad_perm [2,3,0,1] == xor2
//   stage1 : DPP quad_perm [1,0,3,2] == xor1
// Two independent chains (dA, dB): every lane ends with full S_A and S_B.
// Serial cross-lane latency ~160 cyc vs ~770 (7 dependent ds-ops).

#define T_STEPS 1000
#define CIN     784
#define COUT    512
#define CPL     13            // columns per lane (64*13 = 832 >= 784)
#define NROW    512           // one publish byte per row per step
#define VTHR_F   12500.0f
#define PROHIB_F 11250.0f

#define SLOTS_BYTES (T_STEPS * NROW)          // 512000 B
#define CODE_OFFSET 524288                    // 512 KiB >= 512000 B of slots

// ---- prep: zero slot bytes and pack per-(t,lane) 16-byte code slot:
// byte j (j<13) encodes col = lane*13+j: bit0 = x[t][col], bits[2:1] = p.
__global__ __launch_bounds__(256) void prep_kernel(const int* __restrict__ x,
                                                   uint8_t* __restrict__ code,
                                                   uint2* __restrict__ slots2) {
    int gid = blockIdx.x * blockDim.x + threadIdx.x;   // one per (t, lane)
    if (gid >= T_STEPS * 64) return;
    slots2[gid] = make_uint2(0u, 0u);                  // 64000 x 8B = 512000 B
    int t = gid >> 6;
    int lane = gid & 63;
    uint32_t wds[4] = {0u, 0u, 0u, 0u};
    #pragma unroll
    for (int j = 0; j < CPL; ++j) {
        int col = lane * CPL + j;
        uint32_t b = 0u;
        if (col < CIN) {
            int xc = x[t * CIN + col];
            int xp = (t > 0) ? x[(t - 1) * CIN + col] : 0;
            int p = xc ? 2 : ((t == 0) ? 1 : (xp ? 1 : 0));
            b = (uint32_t)((xc & 1) | (p << 1));
        }
        wds[j >> 2] |= b << ((j & 3) * 8);
    }
    ((uint4*)code)[gid] = make_uint4(wds[0], wds[1], wds[2], wds[3]);
}

// scan one gathered uint64 (8 row-bytes): present = high nibble 0xB;
// set = present && hypothesis bit kk.
__device__ __forceinline__ void scan8(unsigned long long gv, int kk,
                                      bool& anyset, bool& allp) {
    anyset = false; allp = true;
    #pragma unroll
    for (int i = 0; i < 8; ++i) {
        uint32_t b = (uint32_t)(gv >> (8 * i)) & 0xFFu;
        bool p = (b & 0xF0u) == 0xB0u;
        allp = allp && p;
        anyset = anyset || (p && (((b >> kk) & 1u) != 0u));
    }
}

__device__ __forceinline__ void decode_code(const uint4& c, float* xf, float* pf) {
    uint32_t cwd[4] = {c.x, c.y, c.z, c.w};
    #pragma unroll
    for (int j = 0; j < CPL; ++j) {
        uint32_t byte = (cwd[j >> 2] >> ((j & 3) * 8)) & 0xFFu;
        xf[j] = (float)(byte & 1u);
        pf[j] = (float)(byte >> 1);
    }
}

// ---- fast bit-exact butterfly building blocks ----
typedef unsigned uint2ev __attribute__((ext_vector_type(2)));

__device__ __forceinline__ float pl32_sum(float v) {
    unsigned a = __builtin_bit_cast(unsigned, v);
    unsigned b = a;
#if __has_builtin(__builtin_amdgcn_permlane32_swap)
    uint2ev r = __builtin_amdgcn_permlane32_swap(a, b, false, false);
    a = r.x; b = r.y;
#else
    asm volatile("v_permlane32_swap_b32 %0, %1" : "+v"(a), "+v"(b));
#endif
    return __builtin_bit_cast(float, a) + __builtin_bit_cast(float, b);
}

__device__ __forceinline__ float pl16_sum(float v) {
    unsigned a = __builtin_bit_cast(unsigned, v);
    unsigned b = a;
#if __has_builtin(__builtin_amdgcn_permlane16_swap)
    uint2ev r = __builtin_amdgcn_permlane16_swap(a, b, false, false);
    a = r.x; b = r.y;
#else
    asm volatile("v_permlane16_swap_b32 %0, %1" : "+v"(a), "+v"(b));
#endif
    return __builtin_bit_cast(float, a) + __builtin_bit_cast(float, b);
}

template <int CTRL>
__device__ __forceinline__ float dpp_xor_sum(float v) {
    int xi = __builtin_bit_cast(int, v);
    int t = __builtin_amdgcn_update_dpp(xi, xi, CTRL, 0xF, 0xF, false);
    return v + __builtin_bit_cast(float, t);
}

__device__ __forceinline__ float swz4_sum(float v) {
    int xi = __builtin_bit_cast(int, v);
    int t = __builtin_amdgcn_ds_swizzle(xi, 0x101F);   // xor4
    return v + __builtin_bit_cast(float, t);
}

// full 64-lane sum, pairing bit-identical to the validated 32,16,8,4,2,1
// xor butterfly (adds commuted only -> bitwise-equal results)
__device__ __forceinline__ float wave_sum(float v) {
    v = pl32_sum(v);                  // stage 32
    v = pl16_sum(v);                  // stage 16
    v = dpp_xor_sum<0x128>(v);        // stage 8: row_ror:8 == xor8
    v = swz4_sum(v);                  // stage 4
    v = dpp_xor_sum<0x4E>(v);         // stage 2: quad_perm [2,3,0,1]
    v = dpp_xor_sum<0xB1>(v);         // stage 1: quad_perm [1,0,3,2]
    return v;                         // every lane holds the full sum
}

__global__ __launch_bounds__(256, 1) void snn_kernel(const float* __restrict__ weight,
                                                     const uint8_t* __restrict__ code,
                                                     uint8_t* __restrict__ slots,
                                                     float* __restrict__ out) {
    const int tid  = threadIdx.x;
    const int wave = tid >> 6;
    const int lane = tid & 63;
    const int row  = blockIdx.x * 4 + wave;    // 512 autonomous waves

    float wA[CPL], wB[CPL];
    #pragma unroll
    for (int j = 0; j < CPL; ++j) {
        int col = lane * CPL + j;
        float v = (col < CIN) ? weight[row * CIN + col] : 0.0f;
        wA[j] = v; wB[j] = v;
    }

    const uint4* code4 = (const uint4*)code;
    float xfc[CPL], pfc[CPL];
    {
        uint4 c0 = code4[lane];
        decode_code(c0, xfc, pfc);
    }
    uint4 cwn = code4[64 + lane];

    float memA = 0.0f, memB = 0.0f;
    bool  psA = true, psB = true;          // spike(-1)=true quirk
    int p2 = 0, p3 = 0;                    // actual P[u-2], P[u-3]
    int hb_m1 = 0, hb_m2 = 0;              // own row hb(u-1), hb(u-2)
    uint32_t myb = 0u;                     // out bits: step v when v%64==lane

    for (int u = 0; u < T_STEPS; ++u) {
        // ---- top-of-loop issues: code load for u+2, gated gather for u-2 ----
        uint4 cw2 = (u + 2 < T_STEPS) ? code4[(size_t)(u + 2) * 64 + lane]
                                      : make_uint4(0u, 0u, 0u, 0u);
        const int kk = (p3 << 1) | p2;                 // (P[u-3]<<1)|P[u-2]
        const bool selfdec = (u >= 2) && (((hb_m2 >> kk) & 1) != 0);
        const unsigned long long* gl =
            (const unsigned long long*)(slots + (size_t)(u >= 2 ? u - 2 : 0) * NROW);
        unsigned long long gv = 0xB0B0B0B0B0B0B0B0ull; // sentinel-passing dummy
        if (u >= 2 && !selfdec)
            gv = __hip_atomic_load(&gl[lane], __ATOMIC_RELAXED,
                                   __HIP_MEMORY_SCOPE_AGENT);

        // ---- dots for both branches (validated per-lane order) ----
        float dA = 0.0f, dB = 0.0f;
        #pragma unroll
        for (int j = 0; j < CPL; ++j) {
            dA += xfc[j] * wA[j];          // exact: x in {0,1}
            dB += xfc[j] * wB[j];
        }

        // ---- fast butterfly: two independent chains, bit-exact pairing ----
        float dotA = wave_sum(dA);
        float dotB = wave_sum(dB);

        // ---- pipelined decode of step u+1's codes (off the w->dot chain) ----
        float xfn[CPL], pfn[CPL];
        decode_code(cwn, xfn, pfn);

        // ---- 4 hypotheses (d = P[u-1] branch, c = P[u] branch) ----
        float sa = memA + dotA;            // reference op order
        float sb = memB + dotB;
        float m00 = fmaxf(sa, 0.0f),            m01 = fmaxf(sa - PROHIB_F, 0.0f);
        float m10 = fmaxf(sb, 0.0f),            m11 = fmaxf(sb - PROHIB_F, 0.0f);
        bool s00 = m00 >= VTHR_F, s01 = m01 >= VTHR_F;
        bool s10 = m10 >= VTHR_F, s11 = m11 >= VTHR_F;
        int hb = (s00 ? 1 : 0) | (s01 ? 2 : 0) | (s10 ? 4 : 0) | (s11 ? 8 : 0);

        // ---- publish own row's hb(u) immediately (fire-and-forget byte) ----
        if (lane == 0)
            __hip_atomic_store(&slots[(size_t)u * NROW + row],
                               (uint8_t)(0xB0u | (uint32_t)hb),
                               __ATOMIC_RELAXED, __HIP_MEMORY_SCOPE_AGENT);

        // ---- resolve P[u-1]: own-row selfdec (88%) or global fallback ----
        int bst = 0;
        if (u >= 2) {
            if (selfdec) {
                bst = 1;                   // own row spiked at u-2
            } else {
                for (;;) {
                    bool anyset, allp;
                    scan8(gv, kk, anyset, allp);
                    if (__any((int)anyset)) { bst = 1; break; }
                    if (__all((int)allp)) { bst = 0; break; }
                    __builtin_amdgcn_s_sleep(1);       // backoff (rare path)
                    gv = __hip_atomic_load(&gl[lane], __ATOMIC_RELAXED,
                                           __HIP_MEMORY_SCOPE_AGENT);
                }
            }
        }
        p3 = p2; p2 = bst;
        hb_m2 = hb_m1; hb_m1 = hb;

        // ---- collapse branch d=bst; record out bit; rebranch over c=P[u] ----
        bool sprv = bst ? psB : psA;                   // actual spike(u-1)
        bool sc0  = bst ? s10 : s00;                   // spike under c=0
        bool sc1  = bst ? s11 : s01;                   // spike under c=1
        float mc0 = bst ? m10 : m00;
        float mc1 = bst ? m11 : m01;

        if (u >= 1) {
            int v = u - 1;
            if ((v & 63) == lane) myb |= (sprv ? 1u : 0u) << (v >> 6);
        }

        memA = sc0 ? 0.0f : mc0;
        memB = sc1 ? 0.0f : mc1;

        // ---- merged if-converted updates (value-exact, no branches) ----
        float s0f = sc0 ? 1.0f : 0.0f;
        float s1f = sc1 ? 1.0f : 0.0f;
        float d0f = (!sc0 && sprv) ? 1.0f : 0.0f;      // mutually exclusive
        float d1f = (!sc1 && sprv) ? 1.0f : 0.0f;
        #pragma unroll
        for (int j = 0; j < CPL; ++j) {
            float base = bst ? wB[j] : wA[j];          // wB==wA when agreed
            float ta = fminf(fmaf(s0f, pfc[j], base), 127.0f);
            wA[j] = fmaxf(fmaf(-d0f, xfc[j], ta), 0.0f);
            float tb = fminf(fmaf(s1f, pfc[j], base), 127.0f);
            wB[j] = fmaxf(fmaf(-d1f, xfc[j], tb), 0.0f);
        }
        psA = sc0; psB = sc1;

        // ---- rotate pipelines ----
        #pragma unroll
        for (int j = 0; j < CPL; ++j) { xfc[j] = xfn[j]; pfc[j] = pfn[j]; }
        cwn = cw2;
    }

    // ---- epilogue: resolve P[T-1], record last bit, write this row's out ----
    {
        const int kk = (p3 << 1) | p2;
        int cst;
        if (((hb_m2 >> kk) & 1) != 0) {
            cst = 1;                       // own row forced the OR
        } else {
            const unsigned long long* gl2 =
                (const unsigned long long*)(slots + (size_t)(T_STEPS - 2) * NROW);
            unsigned long long gv2;
            for (;;) {
                gv2 = __hip_atomic_load(&gl2[lane], __ATOMIC_RELAXED,
                                        __HIP_MEMORY_SCOPE_AGENT);
                bool anyset, allp;
                scan8(gv2, kk, anyset, allp);
                if (__any((int)anyset)) { cst = 1; break; }
                if (__all((int)allp)) { cst = 0; break; }
                __builtin_amdgcn_s_sleep(1);
            }
        }
        bool sr = cst ? psB : psA;
        {
            int v = T_STEPS - 1;
            if ((v & 63) == lane) myb |= (sr ? 1u : 0u) << (v >> 6);
        }
        // write this row's 1000 spike floats from the bit register
        #pragma unroll
        for (int b = 0; b < 16; ++b) {
            int s = b * 64 + lane;
            if (s < T_STEPS)
                out[(size_t)s * COUT + row] = (float)((myb >> b) & 1u);
        }
    }
}

extern "C" void kernel_launch(void* const* d_in, const int* in_sizes, int n_in,
                              void* d_out, int out_size, void* d_ws, size_t ws_size,
                              hipStream_t stream) {
    const int*   x      = (const int*)d_in[0];     // (T,1,CIN) int32
    const float* weight = (const float*)d_in[1];   // (COUT,CIN) f32
    float* out = (float*)d_out;                    // (T,1,COUT) f32

    uint8_t* slots = (uint8_t*)d_ws;
    uint8_t* code  = (uint8_t*)d_ws + CODE_OFFSET;

    int prep_threads = T_STEPS * 64;
    prep_kernel<<<(prep_threads + 255) / 256, 256, 0, stream>>>(x, code,
                                                                (uint2*)slots);
    snn_kernel<<<128, 256, 0, stream>>>(weight, code, slots, out);
}